// Round 3
// baseline (212.354 us; speedup 1.0000x reference)
//
#include <hip/hip_runtime.h>

namespace {
constexpr int N_ = 64, C_ = 512, P_ = 900, K_ = 64;
constexpr size_t TOT_X = (size_t)N_ * C_ * P_;       // 117,964,800 floats
constexpr size_t AT_ELEMS = (size_t)N_ * P_ * K_;    // a' [N][P][K]
constexpr size_t ASUM_OFF = AT_ELEMS;                // asum [N][K]
constexpr size_t WT_OFF   = ASUM_OFF + (size_t)N_ * K_;  // wt [C][K]
}

// --- transpose conv_w [K][C] -> wt [C][K]
__global__ __launch_bounds__(256) void k_transpose_w(const float* __restrict__ w,
                                                     float* __restrict__ wt) {
  int idx = blockIdx.x * 256 + threadIdx.x;
  if (idx < C_ * K_) {
    int c = idx >> 6, k = idx & 63;
    wt[idx] = w[k * C_ + c];
  }
}

// --- phase 1 (LDS-tiled GEMM + fused norm + maxless softmax):
//     block = (n, 128-p tile), all 64 k, c in 16 tiles of 32.
__global__ __launch_bounds__(256) void k_phase1(const float* __restrict__ x,
                                                const float* __restrict__ wt,
                                                float* __restrict__ at,
                                                float* __restrict__ asum) {
  __shared__ float Xl[32][132];
  __shared__ float Wl[32][64];
  __shared__ float Ps[128][9];

  const int n   = blockIdx.y;
  const int p0  = blockIdx.x * 128;
  const int tid = threadIdx.x;
  const int pq  = (tid & 31) * 4;
  const int kg  = tid >> 5;

  float acc[8][4];
  #pragma unroll
  for (int u = 0; u < 8; ++u)
    #pragma unroll
    for (int i = 0; i < 4; ++i) acc[u][i] = 0.f;
  float ssq[4] = {0.f, 0.f, 0.f, 0.f};

  for (int ct = 0; ct < 16; ++ct) {
    const int c0 = ct * 32;
    #pragma unroll
    for (int it = 0; it < 4; ++it) {
      const int idx = tid + it * 256;
      const int c = idx >> 5, pj = (idx & 31) * 4;
      size_t off = ((size_t)n * C_ + c0 + c) * P_ + p0 + pj;
      if (off > TOT_X - 4) off = TOT_X - 4;
      *reinterpret_cast<float4*>(&Xl[c][pj]) =
          *reinterpret_cast<const float4*>(x + off);
    }
    #pragma unroll
    for (int it = 0; it < 2; ++it) {
      const int idx = tid + it * 256;
      const int c = idx >> 4, k4 = (idx & 15) * 4;
      *reinterpret_cast<float4*>(&Wl[c][k4]) =
          *reinterpret_cast<const float4*>(wt + (size_t)(c0 + c) * K_ + k4);
    }
    __syncthreads();
    #pragma unroll 8
    for (int j = 0; j < 32; ++j) {
      const float4 xv = *reinterpret_cast<const float4*>(&Xl[j][pq]);
      const float4 w0 = *reinterpret_cast<const float4*>(&Wl[j][kg * 8]);
      const float4 w1 = *reinterpret_cast<const float4*>(&Wl[j][kg * 8 + 4]);
      const float xs[4] = {xv.x, xv.y, xv.z, xv.w};
      const float ws[8] = {w0.x, w0.y, w0.z, w0.w, w1.x, w1.y, w1.z, w1.w};
      #pragma unroll
      for (int i = 0; i < 4; ++i) ssq[i] = fmaf(xs[i], xs[i], ssq[i]);
      #pragma unroll
      for (int u = 0; u < 8; ++u)
        #pragma unroll
        for (int i = 0; i < 4; ++i)
          acc[u][i] = fmaf(ws[u], xs[i], acc[u][i]);
    }
    __syncthreads();
  }

  float invd[4];
  #pragma unroll
  for (int i = 0; i < 4; ++i)
    invd[i] = 1.f / fmaxf(sqrtf(ssq[i]), 1e-12f);

  float psum[4] = {0.f, 0.f, 0.f, 0.f};
  #pragma unroll
  for (int u = 0; u < 8; ++u)
    #pragma unroll
    for (int i = 0; i < 4; ++i) {
      acc[u][i] = __expf(acc[u][i] * invd[i]);
      psum[i] += acc[u][i];
    }
  #pragma unroll
  for (int i = 0; i < 4; ++i) Ps[pq + i][kg] = psum[i];
  __syncthreads();

  float invs[4];
  #pragma unroll
  for (int i = 0; i < 4; ++i) {
    float s = 0.f;
    #pragma unroll
    for (int g = 0; g < 8; ++g) s += Ps[pq + i][g];
    invs[i] = 1.f / s;
  }

  bool pv[4];
  #pragma unroll
  for (int i = 0; i < 4; ++i) pv[i] = (p0 + pq + i) < P_;

  #pragma unroll
  for (int i = 0; i < 4; ++i) {
    if (pv[i]) {
      float* atp = at + ((size_t)n * P_ + p0 + pq + i) * K_ + kg * 8;
      const float sc = invs[i] * invd[i];
      float4 v0 = make_float4(acc[0][i]*sc, acc[1][i]*sc, acc[2][i]*sc, acc[3][i]*sc);
      float4 v1 = make_float4(acc[4][i]*sc, acc[5][i]*sc, acc[6][i]*sc, acc[7][i]*sc);
      *reinterpret_cast<float4*>(atp)     = v0;
      *reinterpret_cast<float4*>(atp + 4) = v1;
    }
  }

  const int lane = threadIdx.x & 63;
  #pragma unroll
  for (int u = 0; u < 8; ++u) {
    float v = 0.f;
    #pragma unroll
    for (int i = 0; i < 4; ++i)
      v += pv[i] ? acc[u][i] * invs[i] : 0.f;
    #pragma unroll
    for (int off = 16; off > 0; off >>= 1) v += __shfl_xor(v, off, 64);
    if ((lane & 31) == 0) atomicAdd(asum + n * K_ + kg * 8 + u, v);
  }
}

// --- phase 2: vlad[n][k][c] += sum_{p in my 1/3} a'[n][p][k] * x[n][c][p]
//     grid (4 c-tiles, 64 n, 3 p-groups); pc==0 also folds -asum*cent.
//     Accumulate into out via hardware f32 atomics (out pre-zeroed).
__global__ __launch_bounds__(256) void k_phase2(const float* __restrict__ x,
                                                const float* __restrict__ at,
                                                const float* __restrict__ asum,
                                                const float* __restrict__ cent,
                                                float* __restrict__ out) {
  __shared__ float Xl[60][132];   // [j][c]
  __shared__ float Al[60][64];    // [j][k]
  const int n  = blockIdx.y;
  const int c0 = blockIdx.x * 128;
  const int pc = blockIdx.z;
  const int tid = threadIdx.x;
  const int cq = (tid & 31) * 4;
  const int kg = tid >> 5;

  float acc[8][4];
  #pragma unroll
  for (int u = 0; u < 8; ++u)
    #pragma unroll
    for (int i = 0; i < 4; ++i) acc[u][i] = 0.f;

  for (int ch = pc * 5; ch < pc * 5 + 5; ++ch) {
    const int pb = ch * 60;
    for (int idx = tid; idx < 128 * 15; idx += 256) {
      const int c = idx / 15, jq = idx - c * 15;
      const float4 v = *reinterpret_cast<const float4*>(
          x + ((size_t)n * C_ + c0 + c) * P_ + pb + jq * 4);
      Xl[jq*4+0][c] = v.x; Xl[jq*4+1][c] = v.y;
      Xl[jq*4+2][c] = v.z; Xl[jq*4+3][c] = v.w;
    }
    for (int idx = tid; idx < 60 * 16; idx += 256) {
      const int j = idx >> 4, kq = idx & 15;
      *reinterpret_cast<float4*>(&Al[j][kq * 4]) =
          *reinterpret_cast<const float4*>(at + ((size_t)n * P_ + pb + j) * K_ + kq * 4);
    }
    __syncthreads();
    #pragma unroll 4
    for (int j = 0; j < 60; ++j) {
      const float4 xq = *reinterpret_cast<const float4*>(&Xl[j][cq]);
      const float4 a0 = *reinterpret_cast<const float4*>(&Al[j][kg * 8]);
      const float4 a1 = *reinterpret_cast<const float4*>(&Al[j][kg * 8 + 4]);
      const float xs[4] = {xq.x, xq.y, xq.z, xq.w};
      const float as8[8] = {a0.x, a0.y, a0.z, a0.w, a1.x, a1.y, a1.z, a1.w};
      #pragma unroll
      for (int u = 0; u < 8; ++u)
        #pragma unroll
        for (int i = 0; i < 4; ++i)
          acc[u][i] = fmaf(as8[u], xs[i], acc[u][i]);
    }
    __syncthreads();
  }

  #pragma unroll
  for (int u = 0; u < 8; ++u) {
    const int k = kg * 8 + u;
    float4 base = make_float4(0.f, 0.f, 0.f, 0.f);
    if (pc == 0) {
      const float av = asum[n * K_ + k];
      const float4 cv = *reinterpret_cast<const float4*>(cent + k * C_ + c0 + cq);
      base.x = -av * cv.x; base.y = -av * cv.y;
      base.z = -av * cv.z; base.w = -av * cv.w;
    }
    float* op = out + ((size_t)(n * K_ + k)) * C_ + c0 + cq;
    unsafeAtomicAdd(op + 0, acc[u][0] + base.x);
    unsafeAtomicAdd(op + 1, acc[u][1] + base.y);
    unsafeAtomicAdd(op + 2, acc[u][2] + base.z);
    unsafeAtomicAdd(op + 3, acc[u][3] + base.w);
  }
}

extern "C" void kernel_launch(void* const* d_in, const int* in_sizes, int n_in,
                              void* d_out, int out_size, void* d_ws, size_t ws_size,
                              hipStream_t stream) {
  const float* x    = (const float*)d_in[0];
  const float* w    = (const float*)d_in[1];
  const float* cent = (const float*)d_in[2];
  float* out  = (float*)d_out;
  float* ws   = (float*)d_ws;
  float* at   = ws;
  float* asum = ws + ASUM_OFF;
  float* wt   = ws + WT_OFF;

  hipMemsetAsync(asum, 0, (size_t)N_ * K_ * sizeof(float), stream);
  hipMemsetAsync(out, 0, (size_t)out_size * sizeof(float), stream);
  k_transpose_w<<<dim3(128), dim3(256), 0, stream>>>(w, wt);
  k_phase1<<<dim3(8, 64), dim3(256), 0, stream>>>(x, wt, at, asum);
  k_phase2<<<dim3(4, 64, 3), dim3(256), 0, stream>>>(x, at, asum, cent, out);
}

// Round 4
// 83.368 us; speedup vs baseline: 2.5472x; 2.5472x over previous
//
#include <hip/hip_runtime.h>

typedef __attribute__((ext_vector_type(8))) __bf16 bf16x8;
typedef __attribute__((ext_vector_type(4))) float f32x4;

namespace {
constexpr int N_ = 64, C_ = 512, P_ = 900, K_ = 64;
constexpr int PP = 960;                               // padded P for at
constexpr size_t TOT_X = (size_t)N_ * C_ * P_;        // 117,964,800 floats
constexpr size_t AT_BYTES  = (size_t)N_ * K_ * PP * 2;        // bf16 a' [n][k][960]
constexpr size_t ASUM_OFF  = AT_BYTES;                        // f32 [n][k]
constexpr size_t WB_OFF    = ASUM_OFF + (size_t)N_ * K_ * 4;  // bf16 w [k][c]
}

// --- w f32 [K][C] -> bf16 [K][C]
__global__ __launch_bounds__(256) void k_prep_w(const float* __restrict__ w,
                                                __bf16* __restrict__ wb) {
  int i = (blockIdx.x * 256 + threadIdx.x) * 4;
  if (i < K_ * C_) {
    float4 v = *reinterpret_cast<const float4*>(w + i);
    wb[i]   = (__bf16)v.x; wb[i+1] = (__bf16)v.y;
    wb[i+2] = (__bf16)v.z; wb[i+3] = (__bf16)v.w;
  }
}

// --- phase 1: logits^T[k][p] via MFMA, fused ssq + maxless softmax.
//     Block: (p-tile 64, n). 4 waves; wave w owns k rows [16w,16w+16), all 64 p.
__global__ __launch_bounds__(256) void k_phase1(const float* __restrict__ x,
                                                const __bf16* __restrict__ wb,
                                                __bf16* __restrict__ at,
                                                float* __restrict__ asum) {
  __shared__ __bf16 Xb[4][64][8];   // [c/8][p][c%8] — B-frag = ds_read_b128
  __shared__ float ssq_l[64];
  __shared__ float Sw[64][5];
  const int n   = blockIdx.y;
  const int p0  = blockIdx.x * 64;
  const int tid = threadIdx.x;
  const int w   = tid >> 6, l = tid & 63;
  const int l15 = l & 15,  lh = l >> 4;

  // preload A fragments (w rows 16w+l15) for all 16 K-steps: 64 VGPR
  bf16x8 afr[16];
  #pragma unroll
  for (int s = 0; s < 16; ++s)
    afr[s] = *reinterpret_cast<const bf16x8*>(
        wb + (size_t)(16 * w + l15) * C_ + s * 32 + lh * 8);

  f32x4 acc[4] = {};                 // frag t: p=p0+16t+l15, k=16w+lh*4+r
  float sq[4] = {0.f, 0.f, 0.f, 0.f};
  if (tid < 64) ssq_l[tid] = 0.f;

  const int pq = (tid & 15) * 4;     // staging p-offset (fixed per thread)
  #pragma unroll
  for (int s = 0; s < 16; ++s) {
    __syncthreads();
    #pragma unroll
    for (int it = 0; it < 2; ++it) {
      const int idx = tid + it * 256;
      const int c = idx >> 4;        // 0..31
      size_t off = ((size_t)n * C_ + s * 32 + c) * P_ + p0 + pq;
      if (off > TOT_X - 4) off = TOT_X - 4;
      const float4 v = *reinterpret_cast<const float4*>(x + off);
      sq[0] = fmaf(v.x, v.x, sq[0]); sq[1] = fmaf(v.y, v.y, sq[1]);
      sq[2] = fmaf(v.z, v.z, sq[2]); sq[3] = fmaf(v.w, v.w, sq[3]);
      __bf16* dst = &Xb[c >> 3][pq][c & 7];
      dst[0]  = (__bf16)v.x; dst[8]  = (__bf16)v.y;
      dst[16] = (__bf16)v.z; dst[24] = (__bf16)v.w;
    }
    __syncthreads();
    #pragma unroll
    for (int t = 0; t < 4; ++t) {
      bf16x8 b = *reinterpret_cast<const bf16x8*>(&Xb[lh][16 * t + l15][0]);
      acc[t] = __builtin_amdgcn_mfma_f32_16x16x32_bf16(afr[s], b, acc[t], 0, 0, 0);
    }
  }

  #pragma unroll
  for (int q = 0; q < 4; ++q) atomicAdd(&ssq_l[pq + q], sq[q]);
  __syncthreads();

  float invn[4], invs_[4];
  bool valid[4];
  #pragma unroll
  for (int t = 0; t < 4; ++t) {
    invn[t] = 1.f / fmaxf(sqrtf(ssq_l[16 * t + l15]), 1e-12f);
    valid[t] = (p0 + 16 * t + l15) < P_;
    float ps = 0.f;
    #pragma unroll
    for (int r = 0; r < 4; ++r) {
      acc[t][r] = __expf(acc[t][r] * invn[t]);   // maxless: |logit| <= ~0.5
      ps += acc[t][r];
    }
    ps += __shfl_xor(ps, 16, 64);
    ps += __shfl_xor(ps, 32, 64);
    if (l < 16) Sw[16 * t + l][w] = ps;
  }
  __syncthreads();
  #pragma unroll
  for (int t = 0; t < 4; ++t) {
    float S = Sw[16 * t + l15][0] + Sw[16 * t + l15][1] +
              Sw[16 * t + l15][2] + Sw[16 * t + l15][3];
    invs_[t] = 1.f / S;
  }

  // write a' (bf16) and asum atomics
  #pragma unroll
  for (int t = 0; t < 4; ++t) {
    const int p = p0 + 16 * t + l15;
    #pragma unroll
    for (int r = 0; r < 4; ++r) {
      const int k = 16 * w + lh * 4 + r;
      const float ar = acc[t][r] * invs_[t];
      at[((size_t)n * K_ + k) * PP + p] = valid[t] ? (__bf16)(ar * invn[t]) : (__bf16)0.f;
    }
  }
  #pragma unroll
  for (int r = 0; r < 4; ++r) {
    float v = 0.f;
    #pragma unroll
    for (int t = 0; t < 4; ++t)
      v += valid[t] ? acc[t][r] * invs_[t] : 0.f;
    v += __shfl_xor(v, 1, 64); v += __shfl_xor(v, 2, 64);
    v += __shfl_xor(v, 4, 64); v += __shfl_xor(v, 8, 64);
    if (l15 == 0)
      unsafeAtomicAdd(asum + n * K_ + 16 * w + lh * 4 + r, v);
  }
}

// --- phase 2: vlad[k][c] = sum_p a'[k][p] * x_bf16[c][p] - asum[k]*cent[k][c]
//     Block: (c-tile 64, n). 4 waves; wave w owns c cols [16w,16w+16), all 64 k.
__global__ __launch_bounds__(256) void k_phase2(const float* __restrict__ x,
                                                const __bf16* __restrict__ at,
                                                const float* __restrict__ asum,
                                                const float* __restrict__ cent,
                                                float* __restrict__ out) {
  __shared__ __bf16 Al[64][40];   // at-tile [k][p32], padded rows (80 B)
  __shared__ __bf16 Xl[64][40];   // x-tile  [c][p32], padded rows
  const int n   = blockIdx.y;
  const int c0  = blockIdx.x * 64;
  const int tid = threadIdx.x;
  const int w   = tid >> 6, l = tid & 63;
  const int l15 = l & 15,  lh = l >> 4;

  f32x4 acc[4] = {};               // frag m: k=16m+lh*4+r, c=c0+16w+l15

  for (int s = 0; s < 29; ++s) {   // K-dim p: 29 steps of 32 (at pad = 0)
    const int pb = s * 32;
    __syncthreads();
    {
      const int k = tid >> 2, ch = tid & 3;
      bf16x8 v = *reinterpret_cast<const bf16x8*>(
          at + ((size_t)n * K_ + k) * PP + pb + ch * 8);
      *reinterpret_cast<bf16x8*>(&Al[k][ch * 8]) = v;
    }
    #pragma unroll
    for (int it = 0; it < 2; ++it) {
      const int idx = tid + it * 256;
      const int c = idx >> 3, ch = idx & 7;
      size_t off = ((size_t)n * C_ + c0 + c) * P_ + pb + ch * 4;
      if (off > TOT_X - 4) off = TOT_X - 4;
      const float4 v = *reinterpret_cast<const float4*>(x + off);
      __bf16* d = &Xl[c][ch * 4];
      d[0] = (__bf16)v.x; d[1] = (__bf16)v.y;
      d[2] = (__bf16)v.z; d[3] = (__bf16)v.w;
    }
    __syncthreads();
    bf16x8 b = *reinterpret_cast<const bf16x8*>(&Xl[16 * w + l15][lh * 8]);
    #pragma unroll
    for (int m = 0; m < 4; ++m) {
      bf16x8 a = *reinterpret_cast<const bf16x8*>(&Al[16 * m + l15][lh * 8]);
      acc[m] = __builtin_amdgcn_mfma_f32_16x16x32_bf16(a, b, acc[m], 0, 0, 0);
    }
  }

  const int c = c0 + 16 * w + l15;
  #pragma unroll
  for (int m = 0; m < 4; ++m) {
    #pragma unroll
    for (int r = 0; r < 4; ++r) {
      const int k = 16 * m + lh * 4 + r;
      out[((size_t)n * K_ + k) * C_ + c] =
          acc[m][r] - asum[n * K_ + k] * cent[(size_t)k * C_ + c];
    }
  }
}

extern "C" void kernel_launch(void* const* d_in, const int* in_sizes, int n_in,
                              void* d_out, int out_size, void* d_ws, size_t ws_size,
                              hipStream_t stream) {
  const float* x    = (const float*)d_in[0];
  const float* w    = (const float*)d_in[1];
  const float* cent = (const float*)d_in[2];
  float* out = (float*)d_out;
  char* wsb  = (char*)d_ws;
  __bf16* at   = (__bf16*)wsb;
  float*  asum = (float*)(wsb + ASUM_OFF);
  __bf16* wb   = (__bf16*)(wsb + WB_OFF);

  hipMemsetAsync(asum, 0, (size_t)N_ * K_ * sizeof(float), stream);
  k_prep_w<<<dim3(32), dim3(256), 0, stream>>>(w, wb);
  k_phase1<<<dim3(15, 64), dim3(256), 0, stream>>>(x, wb, at, asum);
  k_phase2<<<dim3(8, 64), dim3(256), 0, stream>>>(x, at, asum, cent, out);
}